// Round 5
// baseline (1489.410 us; speedup 1.0000x reference)
//
#include <hip/hip_runtime.h>
#include <stdint.h>

#define T_ 512
#define B_ 64
#define H_ 512
#define L_ 2
#define TBH (T_*B_*H_)   // 16777216
#define BH  (B_*H_)      // 32768
#define NC  8            // time chunks
#define CS  64           // steps per chunk
#define CROWS (CS*B_)    // 4096 rows of [T*B] per chunk

typedef float    f32x4 __attribute__((ext_vector_type(4)));
typedef short    s16x8 __attribute__((ext_vector_type(8)));
typedef short    s16x4 __attribute__((ext_vector_type(4)));
typedef _Float16 h2    __attribute__((ext_vector_type(2)));

static __device__ __forceinline__ short f2bf(float f) {
  uint32_t u = __float_as_uint(f);
  u = (u + 0x7fffu + ((u >> 16) & 1u)) >> 16;  // RNE
  return (short)u;
}

static __device__ __forceinline__ float fdot2(h2 a, h2 b, float c) {
#if __has_builtin(__builtin_amdgcn_fdot2)
  return __builtin_amdgcn_fdot2(a, b, c, false);
#else
  return c + (float)a[0] * (float)b[0] + (float)a[1] * (float)b[1];
#endif
}

// DPP cross-lane on the VALU pipe.
// quad_perm: lane^1 = 0xB1, lane^2 = 0x4E. row_shl:4 = 0x104 (lane i <- i+4),
// row_shr:4 = 0x114 (lane i <- i-4); both stay within the 16-lane row for the
// lanes we select, bound_ctrl zeroes the rest.
template <int CTRL>
static __device__ __forceinline__ float dppf(float v) {
  return __int_as_float(__builtin_amdgcn_mov_dpp(__float_as_int(v), CTRL, 0xF, 0xF, true));
}

// Raw workgroup barrier WITHOUT the vmcnt(0) drain __syncthreads carries.
// LDS ordering guaranteed by the explicit lgkmcnt(0); sched_barrier(0)
// fences prevent hipcc hoisting memory ops across the inline asm (rule #18).
static __device__ __forceinline__ void rawbar() {
  __builtin_amdgcn_sched_barrier(0);
  asm volatile("s_waitcnt lgkmcnt(0)" ::: "memory");
  __builtin_amdgcn_s_barrier();
  __builtin_amdgcn_sched_barrier(0);
}

static __device__ __forceinline__ uint32_t pack2(float a, float b) {
  h2 p = { (_Float16)a, (_Float16)b };
  return __builtin_bit_cast(uint32_t, p);
}

static __device__ __forceinline__ h2 bch(uint32_t u) {
  return __builtin_bit_cast(h2, u);
}

// ---------------------------------------------------------------------------
// GEMM role (unchanged): 512 threads, 256x128 tile, 8 waves as 4Mx2N of 64x64.
// ---------------------------------------------------------------------------
__device__ void gemm_role(char* smem, int rb,
                          const float* __restrict__ In,
                          const float* __restrict__ W,
                          const float* __restrict__ bi,
                          const float* __restrict__ bh,
                          float* __restrict__ Out) {
  constexpr int LDT = 40;
  short* As = (short*)smem;              // 256 x LDT
  short* Bs = (short*)(smem + 256 * LDT * 2);  // 128 x LDT

  const int tid  = threadIdx.x;
  const int m0   = (rb >> 2) * 256;
  const int n0   = (rb & 3) * 128;
  const int wave = tid >> 6, lane = tid & 63;
  const int wm   = (wave >> 1) * 64;
  const int wn   = (wave & 1) * 64;
  const int quad = lane >> 4, tq = lane & 15;

  f32x4 acc[4][4] = {};

  for (int k0 = 0; k0 < 512; k0 += 32) {
    #pragma unroll
    for (int v = 0; v < 4; ++v) {
      int idx = v * 512 + tid;
      int r = idx >> 3, cc = (idx & 7) * 4;
      f32x4 a = *(const f32x4*)(In + (size_t)(m0 + r) * 512 + k0 + cc);
      s16x4 ap = { f2bf(a.x), f2bf(a.y), f2bf(a.z), f2bf(a.w) };
      *(s16x4*)(&As[r * LDT + cc]) = ap;
    }
    #pragma unroll
    for (int v = 0; v < 2; ++v) {
      int idx = v * 512 + tid;
      int r = idx >> 3, cc = (idx & 7) * 4;
      f32x4 b = *(const f32x4*)(W + (size_t)(n0 + r) * 512 + k0 + cc);
      s16x4 bp = { f2bf(b.x), f2bf(b.y), f2bf(b.z), f2bf(b.w) };
      *(s16x4*)(&Bs[r * LDT + cc]) = bp;
    }
    __syncthreads();

    s16x8 af[4], bfr[4];
    #pragma unroll
    for (int mf = 0; mf < 4; ++mf)
      af[mf] = *(const s16x8*)(&As[(wm + mf * 16 + tq) * LDT + quad * 8]);
    #pragma unroll
    for (int nf = 0; nf < 4; ++nf)
      bfr[nf] = *(const s16x8*)(&Bs[(wn + nf * 16 + tq) * LDT + quad * 8]);
    #pragma unroll
    for (int mf = 0; mf < 4; ++mf)
      #pragma unroll
      for (int nf = 0; nf < 4; ++nf)
        acc[mf][nf] = __builtin_amdgcn_mfma_f32_16x16x32_bf16(
            af[mf], bfr[nf], acc[mf][nf], 0, 0, 0);
    __syncthreads();
  }

  #pragma unroll
  for (int nf = 0; nf < 4; ++nf) {
    int col = n0 + wn + nf * 16 + tq;
    float bv = bi[col] + bh[col];
    #pragma unroll
    for (int mf = 0; mf < 4; ++mf) {
      #pragma unroll
      for (int r = 0; r < 4; ++r) {
        int row = m0 + wm + mf * 16 + quad * 4 + r;
        Out[(size_t)row * 512 + col] = acc[mf][nf][r] + bv;
      }
    }
  }
}

// ---------------------------------------------------------------------------
// Recurrence role (one chunk of CS steps). 1 WG = 1 batch, 512 threads.
// Thread t = rg*8 + c: rows rg*8..+7, column chunk c*64..+63.
// Weights: cols 0..47 in regs, cols 48..63 in LDS.
// r5: fine-grained weight pipeline - 8 two-read batches (one k-row each),
// 2 in flight (wa/wb pairs), every consume >=~110cy after issue; butterfly
// partials interleaved to cover the last batches; xor4 moved off LDS onto
// DPP row_shl/shr:4 + select (kills the ~120cy ds_swizzle tail round-trip);
// hbuf write before y-store; raw lgkm-only barrier (r4).
// ---------------------------------------------------------------------------
__device__ void recur_role(char* smem, int b, int chunk,
                           float* __restrict__ xw_y,
                           const float* __restrict__ h0l,
                           const float* __restrict__ Wh,
                           float* __restrict__ hstate) {
  const int tid = threadIdx.x;
  const int c   = tid & 7;
  const int rg  = tid >> 3;

  uint4*    wlds = (uint4*)smem;                     // 16*512 entries, 128 KiB
  _Float16* hbuf = (_Float16*)(smem + 131072);       // [2][8*72]

  h2 wreg[8][24];
  #pragma unroll
  for (int k = 0; k < 8; ++k) {
    const float* wrow = Wh + (size_t)(rg * 8 + k) * 512 + c * 64;
    #pragma unroll
    for (int u = 0; u < 6; ++u) {
      f32x4 w4 = *(const f32x4*)(wrow + u * 8);
      f32x4 w5 = *(const f32x4*)(wrow + u * 8 + 4);
      wreg[k][u * 4 + 0] = h2{(_Float16)w4.x, (_Float16)w4.y};
      wreg[k][u * 4 + 1] = h2{(_Float16)w4.z, (_Float16)w4.w};
      wreg[k][u * 4 + 2] = h2{(_Float16)w5.x, (_Float16)w5.y};
      wreg[k][u * 4 + 3] = h2{(_Float16)w5.z, (_Float16)w5.w};
    }
    #pragma unroll
    for (int p = 0; p < 2; ++p) {
      f32x4 w4 = *(const f32x4*)(wrow + 48 + p * 8);
      f32x4 w5 = *(const f32x4*)(wrow + 48 + p * 8 + 4);
      uint4 pk;
      pk.x = pack2(w4.x, w4.y);
      pk.y = pack2(w4.z, w4.w);
      pk.z = pack2(w5.x, w5.y);
      pk.w = pack2(w5.z, w5.w);
      wlds[(k * 2 + p) * 512 + tid] = pk;
    }
  }

  float hini = (chunk == 0) ? h0l[b * 512 + tid] : hstate[b * 512 + tid];
  hbuf[(tid >> 6) * 72 + (tid & 63)] = (_Float16)hini;   // parity 0 (t0 even)
  __syncthreads();

#define UBLK(HV, W0)                                                        \
  { h2 p0 = bch((HV).x), p1 = bch((HV).y), p2 = bch((HV).z), p3 = bch((HV).w); \
    _Pragma("unroll")                                                       \
    for (int k = 0; k < 8; ++k) {                                           \
      acc[k] = fdot2(wreg[k][(W0) + 0], p0, acc[k]);                        \
      acc[k] = fdot2(wreg[k][(W0) + 1], p1, acc[k]);                        \
      acc[k] = fdot2(wreg[k][(W0) + 2], p2, acc[k]);                        \
      acc[k] = fdot2(wreg[k][(W0) + 3], p3, acc[k]);                        \
    } }

  // load one k-row's 16 streamed cols (2 x b128) into a wt pair
#define WLD2(W0, W1, K)                                                     \
  { W0 = wlds[(2 * (K) + 0) * 512 + tid];                                   \
    W1 = wlds[(2 * (K) + 1) * 512 + tid]; }

  // consume one k-row: 8 fdot2 into acc[K] using h cols 48..63 (q4/r4)
#define CONS2(K, W0, W1)                                                    \
  { float a = acc[(K)];                                                     \
    a = fdot2(bch((W0).x), bch(q4.x), a);                                   \
    a = fdot2(bch((W0).y), bch(q4.y), a);                                   \
    a = fdot2(bch((W0).z), bch(q4.z), a);                                   \
    a = fdot2(bch((W0).w), bch(q4.w), a);                                   \
    a = fdot2(bch((W1).x), bch(r4.x), a);                                   \
    a = fdot2(bch((W1).y), bch(r4.y), a);                                   \
    a = fdot2(bch((W1).z), bch(r4.z), a);                                   \
    a = fdot2(bch((W1).w), bch(r4.w), a);                                   \
    acc[(K)] = a; }

  // butterfly level-1 (lane^1 via DPP quad_perm) for acc pair p
#define XOR1(P)                                                             \
  { float send = (c & 1) ? acc[2 * (P)] : acc[2 * (P) + 1];                 \
    float recv = dppf<0xB1>(send);                                          \
    float keep = (c & 1) ? acc[2 * (P) + 1] : acc[2 * (P)];                 \
    r1v[(P)] = keep + recv; }

  // butterfly level-2 (lane^2) for r2v pair p
#define XOR2(P)                                                             \
  { float send = (c & 2) ? r1v[2 * (P)] : r1v[2 * (P) + 1];                 \
    float recv = dppf<0x4E>(send);                                          \
    float keep = (c & 2) ? r1v[2 * (P) + 1] : r1v[2 * (P)];                 \
    r2v[(P)] = keep + recv; }

  const int t0 = chunk * CS;
  const float* xwp = xw_y + (size_t)b * 512 + tid;
  float xwv = xwp[(size_t)t0 * BH];               // step-t0 value
  float hlast = 0.f;
  for (int t = t0; t < t0 + CS; ++t) {
    const int cur = t & 1, nxt = cur ^ 1;
    // prefetch next step's xw (clamped on last iter); rides across rawbar
    int tn = (t + 1 < t0 + CS) ? t + 1 : t;
    float xwn = xwp[(size_t)tn * BH];

    const _Float16* hc = &hbuf[cur * 8 * 72 + c * 72];
#define HLD(i) (*(const uint4*)(hc + (i) * 8))

    float acc[8] = {0, 0, 0, 0, 0, 0, 0, 0};
    float r1v[4], r2v[2];

    uint4 wa0, wa1, wb0, wb1;
    WLD2(wa0, wa1, 0);               // row 0 in flight
    WLD2(wb0, wb1, 1);               // row 1 in flight
    uint4 q4 = HLD(6), r4 = HLD(7);  // h cols 48..63 (needed by CONS2 first)
    uint4 ha = HLD(0), hbv = HLD(1);

    UBLK(ha, 0);    ha  = HLD(2);    // cols  0..7
    CONS2(0, wa0, wa1);  WLD2(wa0, wa1, 2);
    UBLK(hbv, 4);   hbv = HLD(3);    // cols  8..15
    CONS2(1, wb0, wb1);  WLD2(wb0, wb1, 3);
    UBLK(ha, 8);    ha  = HLD(4);    // cols 16..23
    CONS2(2, wa0, wa1);  WLD2(wa0, wa1, 4);
    UBLK(hbv, 12);  hbv = HLD(5);    // cols 24..31
    CONS2(3, wb0, wb1);  WLD2(wb0, wb1, 5);
    UBLK(ha, 16);                    // cols 32..39
    CONS2(4, wa0, wa1);  WLD2(wa0, wa1, 6);
    UBLK(hbv, 20);                   // cols 40..47
    CONS2(5, wb0, wb1);  WLD2(wb0, wb1, 7);
    CONS2(6, wa0, wa1);
    // butterfly partials cover the final weight batch's latency
    XOR1(0); XOR1(1); XOR1(2); XOR2(0);
    CONS2(7, wb0, wb1);
    XOR1(3); XOR2(1);
    {
      // level-3 (lane^4) on DPP: row_shl:4 / row_shr:4 + select
      float send = (c & 4) ? r2v[0] : r2v[1];
      float su = dppf<0x104>(send);          // lane i <- i+4
      float sd = dppf<0x114>(send);          // lane i <- i-4
      float recv = (c & 4) ? sd : su;
      float keep = (c & 4) ? r2v[1] : r2v[0];
      float dot  = keep + recv;              // full dot for row == tid

      float pre = dot + xwv;
      float e   = __expf(2.f * pre);         // tanh = 1 - 2/(e^{2x}+1)
      float hni = 1.f - 2.f / (e + 1.f);
      hbuf[nxt * 8 * 72 + (tid >> 6) * 72 + (tid & 63)] = (_Float16)hni;
      xw_y[(size_t)t * BH + b * 512 + tid] = hni;
      hlast = hni;
    }
    rawbar();                        // lgkm-only barrier; y-store not drained
    xwv = xwn;
#undef HLD
  }
  hstate[b * 512 + tid] = hlast;   // final chunk leaves h_n in place
#undef UBLK
#undef WLD2
#undef CONS2
#undef XOR1
#undef XOR2
}

// ---------------------------------------------------------------------------
// Pipeline stage s (depth-3 software pipeline over 8 time-chunks):
//   blocks   0..63  R1: recur layer-0, chunk s        (0 <= s <= 7)
//   blocks  64..127 R2: recur layer-1, chunk s-2      (2 <= s <= 9)
//   blocks 128..191 G1: gemm x@W1^T,  chunk s+1       (-1 <= s <= 6)
//   blocks 192..255 G2: gemm y1@W2^T, chunk s-1       (1 <= s <= 8)
// Launched for s = -1..9 (11 launches). Cross-launch visibility via stream
// ordering. h-states live in the hn output slots (final chunk = h_n).
// ---------------------------------------------------------------------------
__global__ __launch_bounds__(512, 1)
void stage(int s,
           const float* __restrict__ x, const float* __restrict__ h0,
           const float* __restrict__ Wih, const float* __restrict__ Whh,
           const float* __restrict__ bih, const float* __restrict__ bhh,
           float* __restrict__ ws, float* __restrict__ out) {
  __shared__ __align__(16) char smem[133376];  // 128K wlds + 2.25K hbuf
  const int role = blockIdx.x >> 6;
  const int rb   = blockIdx.x & 63;
  float* hn = out + (size_t)TBH;

  if (role == 0) {                    // R1
    int cc = s;
    if (cc < 0 || cc >= NC) return;
    recur_role(smem, rb, cc, ws, h0, Whh, hn);
  } else if (role == 1) {             // R2
    int cc = s - 2;
    if (cc < 0 || cc >= NC) return;
    recur_role(smem, rb, cc, out, h0 + BH, Whh + (size_t)H_ * H_, hn + BH);
  } else if (role == 2) {             // G1
    int cc = s + 1;
    if (cc < 0 || cc >= NC) return;
    gemm_role(smem, rb, x + (size_t)cc * CROWS * 512, Wih, bih, bhh,
              ws + (size_t)cc * CROWS * 512);
  } else {                            // G2
    int cc = s - 1;
    if (cc < 0 || cc >= NC) return;
    gemm_role(smem, rb, ws + (size_t)cc * CROWS * 512,
              Wih + (size_t)H_ * H_, bih + H_, bhh + H_,
              out + (size_t)cc * CROWS * 512);
  }
}

// ---------------------------------------------------------------------------
extern "C" void kernel_launch(void* const* d_in, const int* in_sizes, int n_in,
                              void* d_out, int out_size, void* d_ws, size_t ws_size,
                              hipStream_t stream) {
  const float* x   = (const float*)d_in[0];
  const float* h0  = (const float*)d_in[1];
  const float* Wih = (const float*)d_in[2];
  const float* Whh = (const float*)d_in[3];
  const float* bih = (const float*)d_in[4];
  const float* bhh = (const float*)d_in[5];
  float* out = (float*)d_out;
  float* ws  = (float*)d_ws;          // T*B*H*4 = 64 MiB (xw1/y1)

  for (int s = -1; s <= NC + 1; ++s)
    stage<<<256, 512, 0, stream>>>(s, x, h0, Wih, Whh, bih, bhh, ws, out);
}